// Round 5
// baseline (440.857 us; speedup 1.0000x reference)
//
#include <hip/hip_runtime.h>
#include <hip/hip_bf16.h>
#include <math.h>

#define NN 50000
#define NE 600000
#define NF 256
#define NHID 128
#define HEADS 8
#define D0 16
#define NCLS 64
#define NB1 196  // (NN+255)/256

typedef __attribute__((ext_vector_type(8))) short short8;
typedef __attribute__((ext_vector_type(4))) float floatx4;

__device__ __forceinline__ float bf16lo(uint v) { return __uint_as_float((v & 0xffffu) << 16); }
__device__ __forceinline__ float bf16hi(uint v) { return __uint_as_float(v & 0xffff0000u); }
__device__ __forceinline__ uint packbf16(float a, float b) {
    return (uint)__bfloat16_as_ushort(__float2bfloat16(a)) |
           ((uint)__bfloat16_as_ushort(__float2bfloat16(b)) << 16);
}

// ---------------- CSR build ----------------

__global__ void deg_kernel(const int* __restrict__ ei, int* __restrict__ deg) {
    int e = blockIdx.x * 256 + threadIdx.x;
    if (e < NE) atomicAdd(&deg[ei[NE + e]], 1);
}

__global__ void scan1_kernel(const int* __restrict__ deg, int* __restrict__ rs,
                             int* __restrict__ bsum) {
    __shared__ int sh[256];
    int tid = threadIdx.x;
    int i = blockIdx.x * 256 + tid;
    int v = (i < NN) ? deg[i] : 0;
    sh[tid] = v;
    __syncthreads();
    for (int off = 1; off < 256; off <<= 1) {
        int t = (tid >= off) ? sh[tid - off] : 0;
        __syncthreads();
        sh[tid] += t;
        __syncthreads();
    }
    if (i < NN) rs[i] = sh[tid] - v;  // exclusive
    if (tid == 255) bsum[blockIdx.x] = sh[255];
}

__global__ void scan2_kernel(const int* __restrict__ bsum, int* __restrict__ bsumx) {
    __shared__ int sh[256];
    int tid = threadIdx.x;
    int v = (tid < NB1) ? bsum[tid] : 0;
    sh[tid] = v;
    __syncthreads();
    for (int off = 1; off < 256; off <<= 1) {
        int t = (tid >= off) ? sh[tid - off] : 0;
        __syncthreads();
        sh[tid] += t;
        __syncthreads();
    }
    if (tid < NB1) bsumx[tid] = sh[tid] - v;
}

__global__ void scan3_kernel(int* __restrict__ rs, const int* __restrict__ bsumx) {
    int i = blockIdx.x * 256 + threadIdx.x;
    if (i < NN) rs[i] += bsumx[i >> 8];
}

__global__ void scatter_kernel(const int* __restrict__ ei, const int* __restrict__ rs,
                               int* __restrict__ cnt2, int* __restrict__ csr) {
    int e = blockIdx.x * 256 + threadIdx.x;
    if (e >= NE) return;
    int s = ei[e], d = ei[NE + e];
    int pos = rs[d] + atomicAdd(&cnt2[d], 1);
    csr[pos] = s;
}

// ---------------- casts & weight packing ----------------

__global__ void cast_bf16_kernel(const float* __restrict__ in, short* __restrict__ o, int n4) {
    int i = blockIdx.x * 256 + threadIdx.x;
    if (i >= n4) return;
    float4 v = ((const float4*)in)[i];
    short4 r;
    r.x = (short)__bfloat16_as_ushort(__float2bfloat16(v.x));
    r.y = (short)__bfloat16_as_ushort(__float2bfloat16(v.y));
    r.z = (short)__bfloat16_as_ushort(__float2bfloat16(v.z));
    r.w = (short)__bfloat16_as_ushort(__float2bfloat16(v.w));
    ((short4*)o)[i] = r;
}

// Bpack0[((t*8+ks)*64 + l)*8 + j] = bf16( W0[(ks*32 + (l>>4)*8 + j)*128 + t*16 + (l&15)] )
__global__ void pack_w0_kernel(const float* __restrict__ W0, short* __restrict__ Bp) {
    int tid = blockIdx.x * 256 + threadIdx.x;
    if (tid >= 8 * 8 * 64 * 8) return;
    int j = tid & 7, l = (tid >> 3) & 63, ks = (tid >> 9) & 7, t = tid >> 12;
    int k = ks * 32 + (l >> 4) * 8 + j;
    int c = t * 16 + (l & 15);
    Bp[tid] = (short)__bfloat16_as_ushort(__float2bfloat16(W0[(size_t)k * 128 + c]));
}

// Bpack1[((t*32+ks)*64 + l)*8 + j]: kk = ks*32 + (l>>4)*8 + j, c = t*16+(l&15)
__global__ void pack_w1_kernel(const float* __restrict__ W1, short* __restrict__ Bp) {
    int tid = blockIdx.x * 256 + threadIdx.x;
    if (tid >= 4 * 32 * 64 * 8) return;
    int j = tid & 7, l = (tid >> 3) & 63, ks = (tid >> 9) & 31, t = tid >> 14;
    int kk = ks * 32 + (l >> 4) * 8 + j;
    int c = t * 16 + (l & 15);
    float v = W1[(size_t)(kk & 127) * 512 + (kk >> 7) * 64 + c] * 0.125f;
    Bp[tid] = (short)__bfloat16_as_ushort(__float2bfloat16(v));
}

// ---------------- MFMA GEMM (layer 0) ----------------

// h0b[50000,128](bf16) = x_bf16[50000,256] @ W0
__global__ __launch_bounds__(256) void gemm0_mfma(const short* __restrict__ xb,
                                                  const short* __restrict__ Bp,
                                                  ushort* __restrict__ h0b) {
    int lane = threadIdx.x & 63, wave = threadIdx.x >> 6;
    int rg = wave >> 1, cg = wave & 1;
    int q = lane >> 4, c16 = lane & 15;
    int row0 = blockIdx.x * 32 + rg * 16;
    int arow = row0 + c16;
    if (arow > NN - 1) arow = NN - 1;
    const short* ap = xb + (size_t)arow * NF + q * 8;
    floatx4 acc[4] = {};
#pragma unroll
    for (int ks = 0; ks < 8; ++ks) {
        short8 af = *(const short8*)(ap + ks * 32);
#pragma unroll
        for (int tt = 0; tt < 4; ++tt) {
            int t = cg * 4 + tt;
            short8 bf = *(const short8*)(Bp + (((size_t)t * 8 + ks) * 64 + lane) * 8);
            acc[tt] = __builtin_amdgcn_mfma_f32_16x16x32_bf16(af, bf, acc[tt], 0, 0, 0);
        }
    }
#pragma unroll
    for (int r = 0; r < 4; ++r) {
        int grow = row0 + q * 4 + r;
        if (grow >= NN) continue;
#pragma unroll
        for (int tt = 0; tt < 4; ++tt)
            h0b[(size_t)grow * NHID + cg * 64 + tt * 16 + c16] =
                __bfloat16_as_ushort(__float2bfloat16(acc[tt][r]));
    }
}

// ---------------- attention logits ----------------
__global__ void alpha_kernel(const ushort* __restrict__ h, const float* __restrict__ a_s,
                             const float* __restrict__ a_d, float* __restrict__ as_out,
                             float* __restrict__ ad_out) {
    int idx = blockIdx.x * blockDim.x + threadIdx.x;
    if (idx >= NN * HEADS) return;
    int n = idx / HEADS, hh = idx % HEADS;
    const ushort* hp = h + (size_t)n * NHID + hh * D0;
    const float* asp = a_s + hh * D0;
    const float* adp = a_d + hh * D0;
    float s = 0.f, d = 0.f;
    for (int i = 0; i < D0; ++i) {
        float v = __uint_as_float(((uint)hp[i]) << 16);
        s += v * asp[i];
        d += v * adp[i];
    }
    as_out[idx] = s;
    ad_out[idx] = d;
}

// w~[h,k] = sum_d W1[k, h*64+d] * a[h,d]
__global__ void wtil_kernel(const float* __restrict__ W1, const float* __restrict__ aS,
                            const float* __restrict__ aD, float* __restrict__ wS,
                            float* __restrict__ wD) {
    int tid = blockIdx.x * 256 + threadIdx.x;
    if (tid >= HEADS * NHID) return;
    int h = tid / NHID, k = tid % NHID;
    float sS = 0.f, sD = 0.f;
    for (int d2 = 0; d2 < NCLS; ++d2) {
        float w = W1[(size_t)k * (HEADS * NCLS) + h * NCLS + d2];
        sS += w * aS[h * NCLS + d2];
        sD += w * aD[h * NCLS + d2];
    }
    wS[tid] = sS;
    wD[tid] = sD;
}

// as1[n,h] = x1[n,:] . wS[h,:]   (x1 in bf16)
__global__ void alpha1_kernel(const ushort* __restrict__ x1b, const float* __restrict__ wS,
                              const float* __restrict__ wD, float* __restrict__ as_out,
                              float* __restrict__ ad_out) {
    int idx = blockIdx.x * 256 + threadIdx.x;
    if (idx >= NN * HEADS) return;
    int n = idx / HEADS, h = idx % HEADS;
    const ushort* xp = x1b + (size_t)n * NHID;
    const float* sp = wS + h * NHID;
    const float* dp = wD + h * NHID;
    float s = 0.f, d = 0.f;
    for (int k = 0; k < NHID; ++k) {
        float v = __uint_as_float(((uint)xp[k]) << 16);
        s += v * sp[k];
        d += v * dp[k];
    }
    as_out[idx] = s;
    ad_out[idx] = d;
}

// ---------------- fused edge kernel, layer 0 ----------------
// softmax WITHOUT max subtraction (shift-invariant; logits are O(+-6) here)

__global__ __launch_bounds__(256) void fused_edge0(
    const int* __restrict__ rs, const int* __restrict__ deg, const int* __restrict__ csr,
    const ushort* __restrict__ h0b, const float* __restrict__ as0, const float* __restrict__ ad0,
    const float* __restrict__ b0, ushort* __restrict__ x1b) {
    int d = (blockIdx.x * 256 + threadIdx.x) >> 6;
    int lane = threadIdx.x & 63;
    if (d >= NN) return;
    int row = rs[d], dg = deg[d];
    int hl = lane & 7, g = lane >> 3;
    int hp = lane >> 3;  // head owning this lane's dim pair (2*lane, 2*lane+1)
    float adv = ad0[d * 8 + hl];
    float den = 0.f, acc0 = 0.f, acc1 = 0.f;
    for (int base = 0; base < dg; base += 8) {
        int i = base + g;
        int s = (i < dg) ? csr[row + i] : 0;
        float ev = as0[s * 8 + hl] + adv;
        ev = ev > 0.f ? ev : 0.2f * ev;
        float p = (i < dg) ? __expf(ev) : 0.f;
        den += p;
        int nv = dg - base;
        if (nv > 8) nv = 8;
        for (int g2 = 0; g2 < nv; ++g2) {
            int sg = __shfl(s, g2 * 8);
            float ph = __shfl(p, g2 * 8 + hp);
            uint v = *(const uint*)(h0b + (size_t)sg * NHID + 2 * lane);
            acc0 += bf16lo(v) * ph;
            acc1 += bf16hi(v) * ph;
        }
    }
    den += __shfl_xor(den, 8);
    den += __shfl_xor(den, 16);
    den += __shfl_xor(den, 32);
    float dh = __shfl(den, hp);
    float inv = 1.f / (dh + 1e-16f);
    float2 bb = ((const float2*)b0)[lane];
    float o0 = acc0 * inv + bb.x;
    float o1 = acc1 * inv + bb.y;
    o0 = o0 > 0.f ? o0 : expf(o0) - 1.f;
    o1 = o1 > 0.f ? o1 : expf(o1) - 1.f;
    *(uint*)(x1b + (size_t)d * NHID + 2 * lane) = packbf16(o0, o1);
}

// ---------------- fused edge + GEMM + log_softmax, layer 1 ----------------
// Block = 4 waves = 16 dst nodes (50000 = 3125 * 16 exactly).
// Phase 1: wave w aggregates dsts [blk*16+w*4, +4) into LDS (bf16, XOR-swizzled
//          16B chunks -> <=2-way bank aliasing, free).
// Phase 2: 16x1024 @ 1024x64 MFMA, K split 4-ways across waves; partial accs
//          reduced through LDS (reused); log_softmax epilogue, wave w owns reg=w rows.
__global__ __launch_bounds__(256) void fused_edge1_gemm(
    const int* __restrict__ rs, const int* __restrict__ deg, const int* __restrict__ csr,
    const ushort* __restrict__ x1b, const float* __restrict__ as1, const float* __restrict__ ad1,
    const short* __restrict__ Bp, const float* __restrict__ b1, float* __restrict__ out) {
    __shared__ ushort sAGG[16 * 1024];  // 32 KB
    int lane = threadIdx.x & 63, wave = threadIdx.x >> 6;
    int hl = lane & 7, g = lane >> 3;
    int d0 = blockIdx.x * 16;

    // ---- phase 1: aggregate 4 dsts per wave ----
    for (int dd = 0; dd < 4; ++dd) {
        int srow = wave * 4 + dd;
        int d = d0 + srow;
        int row = rs[d], dg = deg[d];
        float adv = ad1[d * 8 + hl];
        float den = 0.f;
        float acc[HEADS][2] = {};
        for (int base = 0; base < dg; base += 8) {
            int i = base + g;
            int s = (i < dg) ? csr[row + i] : 0;
            float ev = as1[s * 8 + hl] + adv;
            ev = ev > 0.f ? ev : 0.2f * ev;
            float p = (i < dg) ? __expf(ev) : 0.f;
            den += p;
            int nv = dg - base;
            if (nv > 8) nv = 8;
            for (int g2 = 0; g2 < nv; ++g2) {
                int sg = __shfl(s, g2 * 8);
                uint v = *(const uint*)(x1b + (size_t)sg * NHID + 2 * lane);
                float lo = bf16lo(v), hi = bf16hi(v);
#pragma unroll
                for (int h = 0; h < HEADS; ++h) {
                    float ph = __shfl(p, g2 * 8 + h);
                    acc[h][0] += lo * ph;
                    acc[h][1] += hi * ph;
                }
            }
        }
        den += __shfl_xor(den, 8);
        den += __shfl_xor(den, 16);
        den += __shfl_xor(den, 32);
#pragma unroll
        for (int h = 0; h < HEADS; ++h) {
            float dh = __shfl(den, h);
            float inv = 1.f / (dh + 1e-16f);
            // column k = 2*lane of head h -> chunk (h*16 + lane/4), swizzled by ^srow
            int idx = srow * 1024 + ((h * 16 + (lane >> 2)) ^ srow) * 8 + (lane & 3) * 2;
            *(uint*)&sAGG[idx] = packbf16(acc[h][0] * inv, acc[h][1] * inv);
        }
    }
    __syncthreads();

    // ---- phase 2: MFMA, K range [wave*256, wave*256+256) ----
    int q = lane >> 4, c16 = lane & 15;
    floatx4 macc[4] = {};
#pragma unroll
    for (int kl = 0; kl < 8; ++kl) {
        int ks = wave * 8 + kl;
        short8 af = *(const short8*)&sAGG[c16 * 1024 + (((ks * 4 + q) ^ c16) * 8)];
#pragma unroll
        for (int t = 0; t < 4; ++t) {
            short8 bf = *(const short8*)(Bp + (((size_t)t * 32 + ks) * 64 + lane) * 8);
            macc[t] = __builtin_amdgcn_mfma_f32_16x16x32_bf16(af, bf, macc[t], 0, 0, 0);
        }
    }
    __syncthreads();  // all waves done reading sAGG
    float* fb = (float*)sAGG;  // reuse as reduction buffer: [w][reg][t][lane] = 16 KB
#pragma unroll
    for (int t = 0; t < 4; ++t)
#pragma unroll
        for (int r = 0; r < 4; ++r)
            fb[wave * 1024 + r * 256 + t * 64 + lane] = macc[t][r];
    __syncthreads();

    // ---- epilogue: wave w handles reg=w rows (rows q*4+w) ----
    float z[4];
    float mx = -INFINITY;
#pragma unroll
    for (int t = 0; t < 4; ++t) {
        float s = fb[0 * 1024 + wave * 256 + t * 64 + lane] +
                  fb[1 * 1024 + wave * 256 + t * 64 + lane] +
                  fb[2 * 1024 + wave * 256 + t * 64 + lane] +
                  fb[3 * 1024 + wave * 256 + t * 64 + lane];
        z[t] = s + b1[t * 16 + c16];
        mx = fmaxf(mx, z[t]);
    }
    mx = fmaxf(mx, __shfl_xor(mx, 1));
    mx = fmaxf(mx, __shfl_xor(mx, 2));
    mx = fmaxf(mx, __shfl_xor(mx, 4));
    mx = fmaxf(mx, __shfl_xor(mx, 8));
    float s = 0.f;
#pragma unroll
    for (int t = 0; t < 4; ++t) s += expf(z[t] - mx);
    s += __shfl_xor(s, 1);
    s += __shfl_xor(s, 2);
    s += __shfl_xor(s, 4);
    s += __shfl_xor(s, 8);
    float lse = mx + logf(s);
    int grow = d0 + q * 4 + wave;
#pragma unroll
    for (int t = 0; t < 4; ++t)
        out[(size_t)grow * NCLS + t * 16 + c16] = z[t] - lse;
}

// ---------------- launch ----------------

extern "C" void kernel_launch(void* const* d_in, const int* in_sizes, int n_in,
                              void* d_out, int out_size, void* d_ws, size_t ws_size,
                              hipStream_t stream) {
    const float* x   = (const float*)d_in[0];
    const int*   ei  = (const int*)d_in[1];
    const float* W0  = (const float*)d_in[2];
    const float* aS0 = (const float*)d_in[3];
    const float* aD0 = (const float*)d_in[4];
    const float* b0  = (const float*)d_in[5];
    const float* W1  = (const float*)d_in[6];
    const float* aS1 = (const float*)d_in[7];
    const float* aD1 = (const float*)d_in[8];
    const float* b1  = (const float*)d_in[9];
    float* out = (float*)d_out;

    char* ws = (char*)d_ws;
    ushort* x1b = (ushort*)ws; ws += (size_t)NN * NHID * 2;           // 12.8 MB
    ushort* h0b = (ushort*)ws; ws += (size_t)NN * NHID * 2;           // 12.8 MB
    short* xb   = (short*)ws; ws += (size_t)NN * NF * 2;              // 25.6 MB
    float* as0  = (float*)ws; ws += (size_t)NN * HEADS * 4;
    float* ad0  = (float*)ws; ws += (size_t)NN * HEADS * 4;
    float* as1  = (float*)ws; ws += (size_t)NN * HEADS * 4;
    float* ad1  = (float*)ws; ws += (size_t)NN * HEADS * 4;
    short* Bp0  = (short*)ws; ws += (size_t)8 * 8 * 64 * 8 * 2;       // 64 KB
    short* Bp1  = (short*)ws; ws += (size_t)4 * 32 * 64 * 8 * 2;      // 128 KB
    float* wS   = (float*)ws; ws += (size_t)HEADS * NHID * 4;
    float* wD   = (float*)ws; ws += (size_t)HEADS * NHID * 4;
    int* deg    = (int*)ws; ws += (size_t)NN * 4;
    int* cnt2   = (int*)ws; ws += (size_t)NN * 4;                     // adjacent to deg
    int* rs     = (int*)ws; ws += (size_t)NN * 4;
    int* bsum   = (int*)ws; ws += 256 * 4;
    int* bsumx  = (int*)ws; ws += 256 * 4;
    int* csr    = (int*)ws; ws += (size_t)NE * 4;                     // 2.4 MB

    const int NH = NN * HEADS;

    // ---- CSR build (shared by both layers) ----
    hipMemsetAsync(deg, 0, (size_t)2 * NN * 4, stream);  // deg + cnt2 in one shot
    deg_kernel<<<(NE + 255) / 256, 256, 0, stream>>>(ei, deg);
    scan1_kernel<<<NB1, 256, 0, stream>>>(deg, rs, bsum);
    scan2_kernel<<<1, 256, 0, stream>>>(bsum, bsumx);
    scan3_kernel<<<NB1, 256, 0, stream>>>(rs, bsumx);
    scatter_kernel<<<(NE + 255) / 256, 256, 0, stream>>>(ei, rs, cnt2, csr);

    // ---- layer 0 ----
    cast_bf16_kernel<<<(NN * NF / 4 + 255) / 256, 256, 0, stream>>>(x, xb, NN * NF / 4);
    pack_w0_kernel<<<(8 * 8 * 64 * 8 + 255) / 256, 256, 0, stream>>>(W0, Bp0);
    gemm0_mfma<<<(NN + 31) / 32, 256, 0, stream>>>(xb, Bp0, h0b);
    alpha_kernel<<<(NH + 255) / 256, 256, 0, stream>>>(h0b, aS0, aD0, as0, ad0);
    fused_edge0<<<(NN + 3) / 4, 256, 0, stream>>>(rs, deg, csr, h0b, as0, ad0, b0, x1b);

    // ---- layer 1 (aggregate x1 in LDS, MFMA + log_softmax fused) ----
    wtil_kernel<<<4, 256, 0, stream>>>(W1, aS1, aD1, wS, wD);
    alpha1_kernel<<<(NH + 255) / 256, 256, 0, stream>>>(x1b, wS, wD, as1, ad1);
    pack_w1_kernel<<<(4 * 32 * 64 * 8 + 255) / 256, 256, 0, stream>>>(W1, Bp1);
    fused_edge1_gemm<<<NN / 16, 256, 0, stream>>>(rs, deg, csr, x1b, as1, ad1, Bp1, b1, out);
}

// Round 6
// 418.394 us; speedup vs baseline: 1.0537x; 1.0537x over previous
//
#include <hip/hip_runtime.h>
#include <hip/hip_bf16.h>
#include <math.h>

#define NN 50000
#define NE 600000
#define NF 256
#define NHID 128
#define HEADS 8
#define D0 16
#define NCLS 64
#define NB1 196  // (NN+255)/256

typedef __attribute__((ext_vector_type(8))) short short8;
typedef __attribute__((ext_vector_type(4))) float floatx4;

__device__ __forceinline__ float bf16lo(uint v) { return __uint_as_float((v & 0xffffu) << 16); }
__device__ __forceinline__ float bf16hi(uint v) { return __uint_as_float(v & 0xffff0000u); }
__device__ __forceinline__ uint packbf16(float a, float b) {
    return (uint)__bfloat16_as_ushort(__float2bfloat16(a)) |
           ((uint)__bfloat16_as_ushort(__float2bfloat16(b)) << 16);
}

// ---------------- CSR build ----------------

__global__ void deg_kernel(const int* __restrict__ ei, int* __restrict__ deg) {
    int e = blockIdx.x * 256 + threadIdx.x;
    if (e < NE) atomicAdd(&deg[ei[NE + e]], 1);
}

__global__ void scan1_kernel(const int* __restrict__ deg, int* __restrict__ rs,
                             int* __restrict__ bsum) {
    __shared__ int sh[256];
    int tid = threadIdx.x;
    int i = blockIdx.x * 256 + tid;
    int v = (i < NN) ? deg[i] : 0;
    sh[tid] = v;
    __syncthreads();
    for (int off = 1; off < 256; off <<= 1) {
        int t = (tid >= off) ? sh[tid - off] : 0;
        __syncthreads();
        sh[tid] += t;
        __syncthreads();
    }
    if (i < NN) rs[i] = sh[tid] - v;  // exclusive
    if (tid == 255) bsum[blockIdx.x] = sh[255];
}

__global__ void scan2_kernel(const int* __restrict__ bsum, int* __restrict__ bsumx) {
    __shared__ int sh[256];
    int tid = threadIdx.x;
    int v = (tid < NB1) ? bsum[tid] : 0;
    sh[tid] = v;
    __syncthreads();
    for (int off = 1; off < 256; off <<= 1) {
        int t = (tid >= off) ? sh[tid - off] : 0;
        __syncthreads();
        sh[tid] += t;
        __syncthreads();
    }
    if (tid < NB1) bsumx[tid] = sh[tid] - v;
}

__global__ void scan3_kernel(int* __restrict__ rs, const int* __restrict__ bsumx) {
    int i = blockIdx.x * 256 + threadIdx.x;
    if (i < NN) rs[i] += bsumx[i >> 8];
}

__global__ void scatter_kernel(const int* __restrict__ ei, const int* __restrict__ rs,
                               int* __restrict__ cnt2, int* __restrict__ csr) {
    int e = blockIdx.x * 256 + threadIdx.x;
    if (e >= NE) return;
    int s = ei[e], d = ei[NE + e];
    int pos = rs[d] + atomicAdd(&cnt2[d], 1);
    csr[pos] = s;
}

// ---------------- casts & weight packing ----------------

__global__ void cast_bf16_kernel(const float* __restrict__ in, short* __restrict__ o, int n4) {
    int i = blockIdx.x * 256 + threadIdx.x;
    if (i >= n4) return;
    float4 v = ((const float4*)in)[i];
    short4 r;
    r.x = (short)__bfloat16_as_ushort(__float2bfloat16(v.x));
    r.y = (short)__bfloat16_as_ushort(__float2bfloat16(v.y));
    r.z = (short)__bfloat16_as_ushort(__float2bfloat16(v.z));
    r.w = (short)__bfloat16_as_ushort(__float2bfloat16(v.w));
    ((short4*)o)[i] = r;
}

// Bpack0[((t*8+ks)*64 + l)*8 + j] = bf16( W0[(ks*32 + (l>>4)*8 + j)*128 + t*16 + (l&15)] )
__global__ void pack_w0_kernel(const float* __restrict__ W0, short* __restrict__ Bp) {
    int tid = blockIdx.x * 256 + threadIdx.x;
    if (tid >= 8 * 8 * 64 * 8) return;
    int j = tid & 7, l = (tid >> 3) & 63, ks = (tid >> 9) & 7, t = tid >> 12;
    int k = ks * 32 + (l >> 4) * 8 + j;
    int c = t * 16 + (l & 15);
    Bp[tid] = (short)__bfloat16_as_ushort(__float2bfloat16(W0[(size_t)k * 128 + c]));
}

// Bpack1[((t*32+ks)*64 + l)*8 + j]: kk = ks*32 + (l>>4)*8 + j, c = t*16+(l&15)
__global__ void pack_w1_kernel(const float* __restrict__ W1, short* __restrict__ Bp) {
    int tid = blockIdx.x * 256 + threadIdx.x;
    if (tid >= 4 * 32 * 64 * 8) return;
    int j = tid & 7, l = (tid >> 3) & 63, ks = (tid >> 9) & 31, t = tid >> 14;
    int kk = ks * 32 + (l >> 4) * 8 + j;
    int c = t * 16 + (l & 15);
    float v = W1[(size_t)(kk & 127) * 512 + (kk >> 7) * 64 + c] * 0.125f;
    Bp[tid] = (short)__bfloat16_as_ushort(__float2bfloat16(v));
}

// ---------------- MFMA GEMMs ----------------

// h0b[50000,128](bf16) = x_bf16[50000,256] @ W0
__global__ __launch_bounds__(256) void gemm0_mfma(const short* __restrict__ xb,
                                                  const short* __restrict__ Bp,
                                                  ushort* __restrict__ h0b) {
    int lane = threadIdx.x & 63, wave = threadIdx.x >> 6;
    int rg = wave >> 1, cg = wave & 1;
    int q = lane >> 4, c16 = lane & 15;
    int row0 = blockIdx.x * 32 + rg * 16;
    int arow = row0 + c16;
    if (arow > NN - 1) arow = NN - 1;
    const short* ap = xb + (size_t)arow * NF + q * 8;
    floatx4 acc[4] = {};
#pragma unroll
    for (int ks = 0; ks < 8; ++ks) {
        short8 af = *(const short8*)(ap + ks * 32);
#pragma unroll
        for (int tt = 0; tt < 4; ++tt) {
            int t = cg * 4 + tt;
            short8 bf = *(const short8*)(Bp + (((size_t)t * 8 + ks) * 64 + lane) * 8);
            acc[tt] = __builtin_amdgcn_mfma_f32_16x16x32_bf16(af, bf, acc[tt], 0, 0, 0);
        }
    }
#pragma unroll
    for (int r = 0; r < 4; ++r) {
        int grow = row0 + q * 4 + r;
        if (grow >= NN) continue;
#pragma unroll
        for (int tt = 0; tt < 4; ++tt)
            h0b[(size_t)grow * NHID + cg * 64 + tt * 16 + c16] =
                __bfloat16_as_ushort(__float2bfloat16(acc[tt][r]));
    }
}

// out[50000,64] = log_softmax( AGG[50000,1024] @ Bpack1 + b1 )
__global__ __launch_bounds__(256) void gemm1_mfma(const short* __restrict__ AGG,
                                                  const short* __restrict__ Bp,
                                                  const float* __restrict__ b1,
                                                  float* __restrict__ out) {
    int lane = threadIdx.x & 63, wave = threadIdx.x >> 6;
    int q = lane >> 4, c16 = lane & 15;
    int row0 = blockIdx.x * 64 + wave * 16;
    int arow = row0 + c16;
    if (arow > NN - 1) arow = NN - 1;
    const short* ap = AGG + (size_t)arow * 1024 + q * 8;
    floatx4 acc[4] = {};
    for (int ks = 0; ks < 32; ++ks) {
        short8 af = *(const short8*)(ap + ks * 32);
#pragma unroll
        for (int t = 0; t < 4; ++t) {
            short8 bf = *(const short8*)(Bp + (((size_t)t * 32 + ks) * 64 + lane) * 8);
            acc[t] = __builtin_amdgcn_mfma_f32_16x16x32_bf16(af, bf, acc[t], 0, 0, 0);
        }
    }
    float bias[4];
#pragma unroll
    for (int t = 0; t < 4; ++t) bias[t] = b1[t * 16 + c16];
#pragma unroll
    for (int r = 0; r < 4; ++r) {
        int grow = row0 + q * 4 + r;
        float z[4];
        float mx = -INFINITY;
#pragma unroll
        for (int t = 0; t < 4; ++t) {
            z[t] = acc[t][r] + bias[t];
            mx = fmaxf(mx, z[t]);
        }
        mx = fmaxf(mx, __shfl_xor(mx, 1));
        mx = fmaxf(mx, __shfl_xor(mx, 2));
        mx = fmaxf(mx, __shfl_xor(mx, 4));
        mx = fmaxf(mx, __shfl_xor(mx, 8));
        float s = 0.f;
#pragma unroll
        for (int t = 0; t < 4; ++t) s += expf(z[t] - mx);
        s += __shfl_xor(s, 1);
        s += __shfl_xor(s, 2);
        s += __shfl_xor(s, 4);
        s += __shfl_xor(s, 8);
        float lse = mx + logf(s);
        if (grow < NN) {
#pragma unroll
            for (int t = 0; t < 4; ++t)
                out[(size_t)grow * NCLS + t * 16 + c16] = z[t] - lse;
        }
    }
}

// ---------------- attention logits ----------------
__global__ void alpha_kernel(const ushort* __restrict__ h, const float* __restrict__ a_s,
                             const float* __restrict__ a_d, float* __restrict__ as_out,
                             float* __restrict__ ad_out) {
    int idx = blockIdx.x * blockDim.x + threadIdx.x;
    if (idx >= NN * HEADS) return;
    int n = idx >> 3, hh = idx & 7;
    const uint4* hp = (const uint4*)(h + (size_t)n * NHID + hh * D0);
    const float* asp = a_s + hh * D0;
    const float* adp = a_d + hh * D0;
    float s = 0.f, d = 0.f;
#pragma unroll
    for (int c = 0; c < 2; ++c) {
        uint4 v = hp[c];
        float f[8] = {bf16lo(v.x), bf16hi(v.x), bf16lo(v.y), bf16hi(v.y),
                      bf16lo(v.z), bf16hi(v.z), bf16lo(v.w), bf16hi(v.w)};
#pragma unroll
        for (int j = 0; j < 8; ++j) {
            s += f[j] * asp[c * 8 + j];
            d += f[j] * adp[c * 8 + j];
        }
    }
    as_out[idx] = s;
    ad_out[idx] = d;
}

// w~[h,k] = sum_d W1[k, h*64+d] * a[h,d]
__global__ void wtil_kernel(const float* __restrict__ W1, const float* __restrict__ aS,
                            const float* __restrict__ aD, float* __restrict__ wS,
                            float* __restrict__ wD) {
    int tid = blockIdx.x * 256 + threadIdx.x;
    if (tid >= HEADS * NHID) return;
    int h = tid / NHID, k = tid % NHID;
    float sS = 0.f, sD = 0.f;
    for (int d2 = 0; d2 < NCLS; ++d2) {
        float w = W1[(size_t)k * (HEADS * NCLS) + h * NCLS + d2];
        sS += w * aS[h * NCLS + d2];
        sD += w * aD[h * NCLS + d2];
    }
    wS[tid] = sS;
    wD[tid] = sD;
}

// as1[n,h] = x1[n,:] . wS[h,:]   (x1 in bf16, uint4-vectorized)
__global__ void alpha1_kernel(const ushort* __restrict__ x1b, const float* __restrict__ wS,
                              const float* __restrict__ wD, float* __restrict__ as_out,
                              float* __restrict__ ad_out) {
    int idx = blockIdx.x * 256 + threadIdx.x;
    if (idx >= NN * HEADS) return;
    int n = idx >> 3, h = idx & 7;
    const uint4* xp = (const uint4*)(x1b + (size_t)n * NHID);
    const float* sp = wS + h * NHID;
    const float* dp = wD + h * NHID;
    float s = 0.f, d = 0.f;
#pragma unroll
    for (int c = 0; c < 16; ++c) {
        uint4 v = xp[c];
        float f[8] = {bf16lo(v.x), bf16hi(v.x), bf16lo(v.y), bf16hi(v.y),
                      bf16lo(v.z), bf16hi(v.z), bf16lo(v.w), bf16hi(v.w)};
#pragma unroll
        for (int j = 0; j < 8; ++j) {
            s += f[j] * sp[c * 8 + j];
            d += f[j] * dp[c * 8 + j];
        }
    }
    as_out[idx] = s;
    ad_out[idx] = d;
}

// ---------------- fused edge kernels (one wave per dst node, single pass) ----------------
// softmax WITHOUT max subtraction (shift-invariant; logits are O(+-6) here).
// Inner gather loop is a COMPILE-TIME 8 iterations (invalid edges have p=0, s=0)
// with loads hoisted ahead of the FMAs -> 8 gathers in flight per chunk.

__global__ __launch_bounds__(256) void fused_edge0(
    const int* __restrict__ rs, const int* __restrict__ deg, const int* __restrict__ csr,
    const ushort* __restrict__ h0b, const float* __restrict__ as0, const float* __restrict__ ad0,
    const float* __restrict__ b0, ushort* __restrict__ x1b) {
    int d = (blockIdx.x * 256 + threadIdx.x) >> 6;
    int lane = threadIdx.x & 63;
    if (d >= NN) return;
    int row = rs[d], dg = deg[d];
    int hl = lane & 7, g = lane >> 3;
    int hp = lane >> 3;  // head owning this lane's dim pair (2*lane, 2*lane+1)
    float adv = ad0[d * 8 + hl];
    float den = 0.f, acc0 = 0.f, acc1 = 0.f;
    for (int base = 0; base < dg; base += 8) {
        int i = base + g;
        int s = (i < dg) ? csr[row + i] : 0;
        float ev = as0[s * 8 + hl] + adv;
        ev = ev > 0.f ? ev : 0.2f * ev;
        float p = (i < dg) ? __expf(ev) : 0.f;
        den += p;
        uint v[8];
#pragma unroll
        for (int g2 = 0; g2 < 8; ++g2) {
            int sg = __shfl(s, g2 * 8);
            v[g2] = *(const uint*)(h0b + (size_t)sg * NHID + 2 * lane);
        }
#pragma unroll
        for (int g2 = 0; g2 < 8; ++g2) {
            float ph = __shfl(p, g2 * 8 + hp);
            acc0 += bf16lo(v[g2]) * ph;
            acc1 += bf16hi(v[g2]) * ph;
        }
    }
    den += __shfl_xor(den, 8);
    den += __shfl_xor(den, 16);
    den += __shfl_xor(den, 32);
    float dh = __shfl(den, hp);
    float inv = 1.f / (dh + 1e-16f);
    float2 bb = ((const float2*)b0)[lane];
    float o0 = acc0 * inv + bb.x;
    float o1 = acc1 * inv + bb.y;
    o0 = o0 > 0.f ? o0 : expf(o0) - 1.f;
    o1 = o1 > 0.f ? o1 : expf(o1) - 1.f;
    *(uint*)(x1b + (size_t)d * NHID + 2 * lane) = packbf16(o0, o1);
}

__global__ __launch_bounds__(256) void fused_edge1(
    const int* __restrict__ rs, const int* __restrict__ deg, const int* __restrict__ csr,
    const ushort* __restrict__ x1b, const float* __restrict__ as1, const float* __restrict__ ad1,
    ushort* __restrict__ AGG) {
    int d = (blockIdx.x * 256 + threadIdx.x) >> 6;
    int lane = threadIdx.x & 63;
    if (d >= NN) return;
    int row = rs[d], dg = deg[d];
    int hl = lane & 7, g = lane >> 3;
    float adv = ad1[d * 8 + hl];
    float den = 0.f;
    float acc[HEADS][2] = {};
    for (int base = 0; base < dg; base += 8) {
        int i = base + g;
        int s = (i < dg) ? csr[row + i] : 0;
        float ev = as1[s * 8 + hl] + adv;
        ev = ev > 0.f ? ev : 0.2f * ev;
        float p = (i < dg) ? __expf(ev) : 0.f;
        den += p;
        uint v[8];
#pragma unroll
        for (int g2 = 0; g2 < 8; ++g2) {
            int sg = __shfl(s, g2 * 8);
            v[g2] = *(const uint*)(x1b + (size_t)sg * NHID + 2 * lane);
        }
#pragma unroll
        for (int g2 = 0; g2 < 8; ++g2) {
            float lo = bf16lo(v[g2]), hi = bf16hi(v[g2]);
#pragma unroll
            for (int h = 0; h < HEADS; ++h) {
                float ph = __shfl(p, g2 * 8 + h);
                acc[h][0] += lo * ph;
                acc[h][1] += hi * ph;
            }
        }
    }
    den += __shfl_xor(den, 8);
    den += __shfl_xor(den, 16);
    den += __shfl_xor(den, 32);
#pragma unroll
    for (int h = 0; h < HEADS; ++h) {
        float dh = __shfl(den, h);
        float inv = 1.f / (dh + 1e-16f);
        *(uint*)(AGG + (size_t)d * 1024 + h * NHID + 2 * lane) =
            packbf16(acc[h][0] * inv, acc[h][1] * inv);
    }
}

// ---------------- launch ----------------

extern "C" void kernel_launch(void* const* d_in, const int* in_sizes, int n_in,
                              void* d_out, int out_size, void* d_ws, size_t ws_size,
                              hipStream_t stream) {
    const float* x   = (const float*)d_in[0];
    const int*   ei  = (const int*)d_in[1];
    const float* W0  = (const float*)d_in[2];
    const float* aS0 = (const float*)d_in[3];
    const float* aD0 = (const float*)d_in[4];
    const float* b0  = (const float*)d_in[5];
    const float* W1  = (const float*)d_in[6];
    const float* aS1 = (const float*)d_in[7];
    const float* aD1 = (const float*)d_in[8];
    const float* b1  = (const float*)d_in[9];
    float* out = (float*)d_out;

    char* ws = (char*)d_ws;
    ushort* x1b = (ushort*)ws; ws += (size_t)NN * NHID * 2;           // 12.8 MB
    ushort* h0b = (ushort*)ws; ws += (size_t)NN * NHID * 2;           // 12.8 MB
    ushort* AGG = (ushort*)ws; ws += (size_t)NN * 1024 * 2;           // 102.4 MB
    short* xb   = (short*)ws; ws += (size_t)NN * NF * 2;              // 25.6 MB
    float* as0  = (float*)ws; ws += (size_t)NN * HEADS * 4;
    float* ad0  = (float*)ws; ws += (size_t)NN * HEADS * 4;
    float* as1  = (float*)ws; ws += (size_t)NN * HEADS * 4;
    float* ad1  = (float*)ws; ws += (size_t)NN * HEADS * 4;
    short* Bp0  = (short*)ws; ws += (size_t)8 * 8 * 64 * 8 * 2;       // 64 KB
    short* Bp1  = (short*)ws; ws += (size_t)4 * 32 * 64 * 8 * 2;      // 128 KB
    float* wS   = (float*)ws; ws += (size_t)HEADS * NHID * 4;
    float* wD   = (float*)ws; ws += (size_t)HEADS * NHID * 4;
    int* deg    = (int*)ws; ws += (size_t)NN * 4;
    int* cnt2   = (int*)ws; ws += (size_t)NN * 4;                     // adjacent to deg
    int* rs     = (int*)ws; ws += (size_t)NN * 4;
    int* bsum   = (int*)ws; ws += 256 * 4;
    int* bsumx  = (int*)ws; ws += 256 * 4;
    int* csr    = (int*)ws; ws += (size_t)NE * 4;                     // 2.4 MB

    const int NH = NN * HEADS;

    // ---- CSR build (shared by both layers) ----
    hipMemsetAsync(deg, 0, (size_t)2 * NN * 4, stream);  // deg + cnt2 in one shot
    deg_kernel<<<(NE + 255) / 256, 256, 0, stream>>>(ei, deg);
    scan1_kernel<<<NB1, 256, 0, stream>>>(deg, rs, bsum);
    scan2_kernel<<<1, 256, 0, stream>>>(bsum, bsumx);
    scan3_kernel<<<NB1, 256, 0, stream>>>(rs, bsumx);
    scatter_kernel<<<(NE + 255) / 256, 256, 0, stream>>>(ei, rs, cnt2, csr);

    // ---- layer 0 ----
    cast_bf16_kernel<<<(NN * NF / 4 + 255) / 256, 256, 0, stream>>>(x, xb, NN * NF / 4);
    pack_w0_kernel<<<(8 * 8 * 64 * 8 + 255) / 256, 256, 0, stream>>>(W0, Bp0);
    gemm0_mfma<<<(NN + 31) / 32, 256, 0, stream>>>(xb, Bp0, h0b);
    alpha_kernel<<<(NH + 255) / 256, 256, 0, stream>>>(h0b, aS0, aD0, as0, ad0);
    fused_edge0<<<(NN + 3) / 4, 256, 0, stream>>>(rs, deg, csr, h0b, as0, ad0, b0, x1b);

    // ---- layer 1 (aggregate x1, GEMM after) ----
    wtil_kernel<<<4, 256, 0, stream>>>(W1, aS1, aD1, wS, wD);
    alpha1_kernel<<<(NH + 255) / 256, 256, 0, stream>>>(x1b, wS, wD, as1, ad1);
    fused_edge1<<<(NN + 3) / 4, 256, 0, stream>>>(rs, deg, csr, x1b, as1, ad1, AGG);
    pack_w1_kernel<<<(4 * 32 * 64 * 8 + 255) / 256, 256, 0, stream>>>(W1, Bp1);
    gemm1_mfma<<<(NN + 63) / 64, 256, 0, stream>>>((const short*)AGG, Bp1, b1, out);
}